// Round 1
// baseline (211.294 us; speedup 1.0000x reference)
//
#include <hip/hip_runtime.h>
#include <stdint.h>

#define H 256
#define EPS 1e-8f

typedef __bf16 bf16x8 __attribute__((ext_vector_type(8)));
typedef float  f32x4  __attribute__((ext_vector_type(4)));

__device__ __forceinline__ unsigned short f2bf(float f) {
  unsigned u = __builtin_bit_cast(unsigned, f);
  u += 0x7FFFu + ((u >> 16) & 1u);            // round-to-nearest-even
  return (unsigned short)(u >> 16);
}
__device__ __forceinline__ float bflo(unsigned u){ return __builtin_bit_cast(float, u << 16); }
__device__ __forceinline__ float bfhi(unsigned u){ return __builtin_bit_cast(float, u & 0xFFFF0000u); }

__device__ __forceinline__ void g2l16(const void* g, void* l) {
  __builtin_amdgcn_global_load_lds((__attribute__((address_space(1))) void*)g,
                                   (__attribute__((address_space(3))) void*)l, 16, 0, 0);
}

// fp32 -> bf16 bits, zero-fill beyond `valid` (row padding for GEMM tiles)
__global__ __launch_bounds__(256) void conv_bf16_kernel(
    const float* __restrict__ src, unsigned short* __restrict__ dst, int valid, int total) {
  int i = (blockIdx.x * 256 + threadIdx.x) * 4;
  if (i >= total) return;
  float4 v = make_float4(0.f, 0.f, 0.f, 0.f);
  if (i < valid) v = *(const float4*)(src + i);
  ushort4 o;
  o.x = f2bf(v.x); o.y = f2bf(v.y); o.z = f2bf(v.z); o.w = f2bf(v.w);
  *(ushort4*)(dst + i) = o;
}

// C[Mp,256] = act(A[Mp,256] @ B[256,256]^T + bias), bf16 in/out, fp32 accum.
// m97-style: 128x128 block tile, 4 waves in 2x2, each wave 4x4 MFMA subtiles,
// BK=32, global_load_lds width-16 staging, single-buffered LDS.
template<bool RELU>
__global__ __launch_bounds__(256) void gemm_bt_kernel(
    const unsigned short* __restrict__ A,
    const unsigned short* __restrict__ B,
    const float* __restrict__ bias,
    unsigned short* __restrict__ C) {
  __shared__ unsigned short sA[128 * 32];
  __shared__ unsigned short sB[128 * 32];
  const int tid  = threadIdx.x;
  const int wave = tid >> 6, lane = tid & 63;
  const int quad = lane >> 4, l16 = lane & 15;
  const int wm = wave & 1, wn = wave >> 1;
  const size_t bm = blockIdx.x, bn = blockIdx.y;

  // staging: per wave 2 calls per tile; call c covers rows (wave*2+c)*16 .. +16
  const int srow0 = (wave * 2 + 0) * 16 + (lane >> 2);
  const int srow1 = (wave * 2 + 1) * 16 + (lane >> 2);
  const int kch   = (lane & 3) * 8;                      // 8 bf16 = 16 B chunk
  const unsigned short* gA0 = A + ((bm * 128 + srow0) * H + kch);
  const unsigned short* gA1 = A + ((bm * 128 + srow1) * H + kch);
  const unsigned short* gB0 = B + ((bn * 128 + srow0) * H + kch);
  const unsigned short* gB1 = B + ((bn * 128 + srow1) * H + kch);
  unsigned short* lA0 = sA + (wave * 2 + 0) * 512 + lane * 8;
  unsigned short* lA1 = sA + (wave * 2 + 1) * 512 + lane * 8;
  unsigned short* lB0 = sB + (wave * 2 + 0) * 512 + lane * 8;
  unsigned short* lB1 = sB + (wave * 2 + 1) * 512 + lane * 8;

  f32x4 acc[4][4];
#pragma unroll
  for (int i = 0; i < 4; i++)
#pragma unroll
    for (int j = 0; j < 4; j++) acc[i][j] = (f32x4){0.f, 0.f, 0.f, 0.f};

#pragma unroll
  for (int kk = 0; kk < H / 32; ++kk) {
    const int k0 = kk * 32;
    if (kk) __syncthreads();                 // prior ds_reads done before overwrite
    g2l16(gA0 + k0, lA0);
    g2l16(gA1 + k0, lA1);
    g2l16(gB0 + k0, lB0);
    g2l16(gB1 + k0, lB1);
    __syncthreads();                         // vmcnt(0) drain: LDS tiles visible

    bf16x8 af[4], bfr[4];
#pragma unroll
    for (int i = 0; i < 4; i++)
      af[i] = *(const bf16x8*)(sA + ((wm * 64 + i * 16 + l16) * 32 + quad * 8));
#pragma unroll
    for (int j = 0; j < 4; j++)
      bfr[j] = *(const bf16x8*)(sB + ((wn * 64 + j * 16 + l16) * 32 + quad * 8));
#pragma unroll
    for (int i = 0; i < 4; i++)
#pragma unroll
      for (int j = 0; j < 4; j++)
        acc[i][j] = __builtin_amdgcn_mfma_f32_16x16x32_bf16(af[i], bfr[j], acc[i][j], 0, 0, 0);
  }

  // epilogue: C/D layout col=lane&15, row=quad*4+reg (m89/m91-verified)
  const int row_base = (int)bm * 128 + wm * 64;
  const int col_base = (int)bn * 128 + wn * 64;
#pragma unroll
  for (int j = 0; j < 4; j++) {
    const int col = col_base + j * 16 + l16;
    const float bv = bias[col];
#pragma unroll
    for (int i = 0; i < 4; i++) {
#pragma unroll
      for (int r = 0; r < 4; r++) {
        const int row = row_base + i * 16 + quad * 4 + r;
        float v = acc[i][j][r] + bv;
        if (RELU) v = fmaxf(v, 0.f);
        C[(size_t)row * H + col] = f2bf(v);
      }
    }
  }
}

// per-node reciprocal norm: rn[i] = 1/max(||g_i||, eps), one wave per row
__global__ __launch_bounds__(256) void rownorm_kernel(
    const unsigned short* __restrict__ g, float* __restrict__ rn, int n) {
  int row = blockIdx.x * 4 + (threadIdx.x >> 6);
  if (row >= n) return;
  int lane = threadIdx.x & 63;
  uint2 a = ((const uint2*)(g + (size_t)row * H))[lane];
  float x0 = bflo(a.x), x1 = bfhi(a.x), x2 = bflo(a.y), x3 = bfhi(a.y);
  float ss = x0 * x0 + x1 * x1 + x2 * x2 + x3 * x3;
#pragma unroll
  for (int off = 32; off; off >>= 1) ss += __shfl_down(ss, off, 64);
  if (lane == 0) rn[row] = 1.f / fmaxf(sqrtf(ss), EPS);
}

// one wave per edge: gather both g rows (512 B each), fp32 dot, scale by rnorms
__global__ __launch_bounds__(256) void edge_cos_kernel(
    const int* __restrict__ ei, const unsigned short* __restrict__ g,
    const float* __restrict__ rn, float* __restrict__ out, int E) {
  int e = blockIdx.x * 4 + (threadIdx.x >> 6);
  if (e >= E) return;
  int lane = threadIdx.x & 63;
  int c = ei[e], r = ei[E + e];
  uint2 a = ((const uint2*)(g + (size_t)c * H))[lane];
  uint2 b = ((const uint2*)(g + (size_t)r * H))[lane];
  float d = bflo(a.x) * bflo(b.x) + bfhi(a.x) * bfhi(b.x) +
            bflo(a.y) * bflo(b.y) + bfhi(a.y) * bfhi(b.y);
#pragma unroll
  for (int off = 32; off; off >>= 1) d += __shfl_down(d, off, 64);
  if (lane == 0) out[e] = d * rn[c] * rn[r];
}

extern "C" void kernel_launch(void* const* d_in, const int* in_sizes, int n_in,
                              void* d_out, int out_size, void* d_ws, size_t ws_size,
                              hipStream_t stream) {
  const float* emb = (const float*)d_in[0];
  const int*   ei  = (const int*)d_in[1];
  const float* W1  = (const float*)d_in[2];
  const float* b1  = (const float*)d_in[3];
  const float* W2  = (const float*)d_in[4];
  const float* b2  = (const float*)d_in[5];
  float* out = (float*)d_out;

  const int NH = in_sizes[0];              // N*H
  const int N  = NH / H;                   // 50000
  const int E  = in_sizes[1] / 2;          // 300000
  const int Mp = ((N + 127) / 128) * 128;  // 50048

  char* ws = (char*)d_ws;
  unsigned short* embB = (unsigned short*)ws; ws += (size_t)Mp * H * 2;
  unsigned short* hB   = (unsigned short*)ws; ws += (size_t)Mp * H * 2;
  unsigned short* gB   = (unsigned short*)ws; ws += (size_t)Mp * H * 2;
  unsigned short* w1B  = (unsigned short*)ws; ws += (size_t)H * H * 2;
  unsigned short* w2B  = (unsigned short*)ws; ws += (size_t)H * H * 2;
  float* rn            = (float*)ws;

  conv_bf16_kernel<<<(Mp * H / 4 + 255) / 256, 256, 0, stream>>>(emb, embB, NH, Mp * H);
  conv_bf16_kernel<<<(H * H / 4 + 255) / 256, 256, 0, stream>>>(W1, w1B, H * H, H * H);
  conv_bf16_kernel<<<(H * H / 4 + 255) / 256, 256, 0, stream>>>(W2, w2B, H * H, H * H);

  dim3 ggrid(Mp / 128, H / 128);
  gemm_bt_kernel<true ><<<ggrid, 256, 0, stream>>>(embB, w1B, b1, hB);
  gemm_bt_kernel<false><<<ggrid, 256, 0, stream>>>(hB, w2B, b2, gB);

  rownorm_kernel<<<(N + 3) / 4, 256, 0, stream>>>(gB, rn, N);
  edge_cos_kernel<<<(E + 3) / 4, 256, 0, stream>>>(ei, gB, rn, out, E);
}